// Round 1
// baseline (343.474 us; speedup 1.0000x reference)
//
#include <hip/hip_runtime.h>

#define L_DIM 2048
#define B_DIM 8
#define DD    1024
#define M_DIM 16384     // L*B
#define N_DIM 3072      // 3*D
#define K_DIM 1024
#define CH    8192      // B*D channels
#define NSEG  64
#define LSEG  32
#define LN_EPS 1e-5f

typedef __attribute__((ext_vector_type(8))) short bf16x8;
typedef __attribute__((ext_vector_type(4))) float f32x4;

__device__ __forceinline__ unsigned short f2bf(float f){
  unsigned u = __float_as_uint(f);
  u += 0x7fffu + ((u >> 16) & 1u);
  return (unsigned short)(u >> 16);
}
__device__ __forceinline__ float bf2f(unsigned short h){
  return __uint_as_float(((unsigned)h) << 16);
}
__device__ __forceinline__ float fsigmoid(float z){ return 1.0f/(1.0f + __expf(-z)); }
__device__ __forceinline__ float ftanh(float z){ return 1.0f - 2.0f/(1.0f + __expf(2.0f*z)); }

// ---------------- LayerNorm: x[M,1024] fp32 -> xn[M,1024] bf16 ----------------
__global__ __launch_bounds__(256) void ln_kernel(const float* __restrict__ x,
                                                 const float* __restrict__ g,
                                                 const float* __restrict__ bta,
                                                 unsigned short* __restrict__ xn)
{
  int row = blockIdx.x;
  int tid = threadIdx.x;
  const float4* xr = (const float4*)(x + (size_t)row * DD);
  float4 v = xr[tid];
  float s  = v.x + v.y + v.z + v.w;
  float sq = v.x*v.x + v.y*v.y + v.z*v.z + v.w*v.w;
  #pragma unroll
  for (int off = 32; off > 0; off >>= 1) {
    s  += __shfl_down(s,  off, 64);
    sq += __shfl_down(sq, off, 64);
  }
  __shared__ float ls[4], lsq[4];
  int wave = tid >> 6, lane = tid & 63;
  if (lane == 0) { ls[wave] = s; lsq[wave] = sq; }
  __syncthreads();
  s  = ls[0] + ls[1] + ls[2] + ls[3];
  sq = lsq[0] + lsq[1] + lsq[2] + lsq[3];
  float mean = s * (1.0f / DD);
  float var  = sq * (1.0f / DD) - mean * mean;
  float rstd = rsqrtf(var + LN_EPS);
  float4 gg = ((const float4*)g)[tid];
  float4 bb = ((const float4*)bta)[tid];
  ushort4 o;
  o.x = f2bf((v.x - mean) * rstd * gg.x + bb.x);
  o.y = f2bf((v.y - mean) * rstd * gg.y + bb.y);
  o.z = f2bf((v.z - mean) * rstd * gg.z + bb.z);
  o.w = f2bf((v.w - mean) * rstd * gg.w + bb.w);
  ((ushort4*)(xn + (size_t)row * DD))[tid] = o;
}

// ---------------- W fp32 [3072,1024] -> bf16 same layout ----------------
__global__ __launch_bounds__(256) void wconv_kernel(const float* __restrict__ W,
                                                    unsigned short* __restrict__ wb)
{
  int gid = blockIdx.x * 256 + threadIdx.x;   // 786432 float4 groups
  float4 v = ((const float4*)W)[gid];
  ushort4 o;
  o.x = f2bf(v.x); o.y = f2bf(v.y); o.z = f2bf(v.z); o.w = f2bf(v.w);
  ((ushort4*)wb)[gid] = o;
}

// ---------------- GEMM: ufr = xn * W^T + b, fused activations ----------------
// A [M,K] bf16 row-major, Bw [N,K] bf16 row-major (B^T layout).
// Epilogue: n<1024 -> u=tanh ; 1024<=n<2048 -> f=sigmoid ; else r=sigmoid
#define BM 128
#define BN 128
#define BK 32

#define GLDS16(gp, lp) __builtin_amdgcn_global_load_lds( \
    (const __attribute__((address_space(1))) void*)(gp), \
    (__attribute__((address_space(3))) void*)(lp), 16, 0, 0)

__global__ __launch_bounds__(256) void gemm_gates(const unsigned short* __restrict__ A,
                                                  const unsigned short* __restrict__ Bw,
                                                  const float* __restrict__ bias,
                                                  unsigned short* __restrict__ u_t,
                                                  unsigned short* __restrict__ f_g,
                                                  unsigned short* __restrict__ r_g)
{
  __shared__ unsigned short sA[BM * BK];   // 8 KB
  __shared__ unsigned short sB[BN * BK];   // 8 KB
  int tid  = threadIdx.x;
  int wave = tid >> 6, lane = tid & 63;
  int bm0 = blockIdx.x * BM;
  int bn0 = blockIdx.y * BN;

  f32x4 zero = {0.f, 0.f, 0.f, 0.f};
  f32x4 acc[4][4];
  #pragma unroll
  for (int i = 0; i < 4; i++)
    #pragma unroll
    for (int j = 0; j < 4; j++) acc[i][j] = zero;

  // staging: each wave stages 32 rows (2 issues x 16 rows) of A and of B
  int q  = lane >> 2;        // row within 16-row issue
  int rr = lane & 3;         // 8-element column chunk
  const unsigned short* a_base = A  + (size_t)(bm0 + wave * 32) * K_DIM + rr * 8;
  const unsigned short* b_base = Bw + (size_t)(bn0 + wave * 32) * K_DIM + rr * 8;

  int wm = (wave & 1) * 64, wn = (wave >> 1) * 64;
  int fm = lane & 15, quad = lane >> 4;

  for (int k0 = 0; k0 < K_DIM; k0 += BK) {
    #pragma unroll
    for (int i = 0; i < 2; i++) {
      // lane l writes LDS at (uniform base) + l*16 bytes = row q, cols rr*8..rr*8+8
      GLDS16(a_base + (size_t)(i * 16 + q) * K_DIM + k0, &sA[(wave * 32 + i * 16) * BK]);
      GLDS16(b_base + (size_t)(i * 16 + q) * K_DIM + k0, &sB[(wave * 32 + i * 16) * BK]);
    }
    __syncthreads();

    bf16x8 af[4], bfr[4];
    #pragma unroll
    for (int i = 0; i < 4; i++) {
      af[i]  = *(const bf16x8*)&sA[(wm + i * 16 + fm) * BK + quad * 8];
      bfr[i] = *(const bf16x8*)&sB[(wn + i * 16 + fm) * BK + quad * 8];
    }
    #pragma unroll
    for (int mi = 0; mi < 4; mi++)
      #pragma unroll
      for (int ni = 0; ni < 4; ni++)
        acc[mi][ni] = __builtin_amdgcn_mfma_f32_16x16x32_bf16(af[mi], bfr[ni], acc[mi][ni], 0, 0, 0);
    __syncthreads();
  }

  // epilogue: C/D layout col=lane&15 (n), row=quad*4+reg (m)
  #pragma unroll
  for (int ni = 0; ni < 4; ni++) {
    int n = bn0 + wn + ni * 16 + fm;
    float bia = bias[n];
    int slice = n >> 10;            // 0:u 1:f 2:r (uniform per block)
    int nd = n & 1023;
    unsigned short* dst = (slice == 0) ? u_t : ((slice == 1) ? f_g : r_g);
    #pragma unroll
    for (int mi = 0; mi < 4; mi++) {
      #pragma unroll
      for (int reg = 0; reg < 4; reg++) {
        int m = bm0 + wm + mi * 16 + quad * 4 + reg;
        float v = acc[mi][ni][reg] + bia;
        float act = (slice == 0) ? ftanh(v) : fsigmoid(v);
        dst[(size_t)m * DD + nd] = f2bf(act);
      }
    }
  }
}

// ---------------- scan pass 1: per-segment affine summary ----------------
// c_out = P * c_in + E over each 32-step segment
__global__ __launch_bounds__(256) void scan_pass1(const unsigned short* __restrict__ f_g,
                                                  const unsigned short* __restrict__ u_t,
                                                  float* __restrict__ P, float* __restrict__ E)
{
  int ch  = blockIdx.x * 256 + threadIdx.x;
  int seg = blockIdx.y;
  size_t g = (size_t)seg * LSEG * CH + ch;
  float p = 1.f, e = 0.f;
  #pragma unroll 8
  for (int i = 0; i < LSEG; i++) {
    float f = bf2f(f_g[g]);
    float u = bf2f(u_t[g]);
    e = f * e + (1.f - f) * u;
    p *= f;
    g += CH;
  }
  P[(size_t)seg * CH + ch] = p;
  E[(size_t)seg * CH + ch] = e;
}

// ---------------- scan pass 2: scan segment summaries, emit last_c ----------------
__global__ __launch_bounds__(256) void scan_pass2(const float* __restrict__ P,
                                                  const float* __restrict__ E,
                                                  const float* __restrict__ c0,
                                                  float* __restrict__ Cini,
                                                  float* __restrict__ lastc)
{
  int ch = blockIdx.x * 256 + threadIdx.x;
  float c = c0[ch];
  #pragma unroll 8
  for (int s = 0; s < NSEG; s++) {
    Cini[(size_t)s * CH + ch] = c;
    c = P[(size_t)s * CH + ch] * c + E[(size_t)s * CH + ch];
  }
  lastc[ch] = c;
}

// ---------------- scan pass 3: replay with true init + fused output ----------------
__global__ __launch_bounds__(256) void scan_pass3(const unsigned short* __restrict__ f_g,
                                                  const unsigned short* __restrict__ u_t,
                                                  const unsigned short* __restrict__ r_g,
                                                  const float* __restrict__ x,
                                                  const unsigned short* __restrict__ xn,
                                                  const float* __restrict__ Cini,
                                                  float* __restrict__ out)
{
  int ch  = blockIdx.x * 256 + threadIdx.x;
  int seg = blockIdx.y;
  float c = Cini[(size_t)seg * CH + ch];
  size_t g = (size_t)seg * LSEG * CH + ch;
  #pragma unroll 4
  for (int i = 0; i < LSEG; i++) {
    float f = bf2f(f_g[g]);
    float u = bf2f(u_t[g]);
    float r = bf2f(r_g[g]);
    c = f * c + (1.f - f) * u;
    float h = r * ftanh(c) + (1.f - r) * bf2f(xn[g]);
    out[g] = x[g] + h;
    g += CH;
  }
}

extern "C" void kernel_launch(void* const* d_in, const int* in_sizes, int n_in,
                              void* d_out, int out_size, void* d_ws, size_t ws_size,
                              hipStream_t stream) {
  const float* x    = (const float*)d_in[0];
  const float* c0   = (const float*)d_in[1];
  const float* W    = (const float*)d_in[2];
  const float* bias = (const float*)d_in[3];
  const float* ln_g = (const float*)d_in[4];
  const float* ln_b = (const float*)d_in[5];
  float* out = (float*)d_out;

  char* ws = (char*)d_ws;
  // workspace layout (bytes)
  unsigned short* xn  = (unsigned short*)(ws);                 // 33,554,432
  unsigned short* wb  = (unsigned short*)(ws + 33554432ULL);   //  6,291,456
  unsigned short* u_t = (unsigned short*)(ws + 39845888ULL);   // 33,554,432
  unsigned short* f_g = (unsigned short*)(ws + 73400320ULL);   // 33,554,432
  unsigned short* r_g = (unsigned short*)(ws + 106954752ULL);  // 33,554,432
  float* Pseg = (float*)(ws + 140509184ULL);                   //  2,097,152
  float* Eseg = (float*)(ws + 142606336ULL);                   //  2,097,152
  float* Cini = (float*)(ws + 144703488ULL);                   //  2,097,152  (end ~146.8 MB)

  ln_kernel   <<<M_DIM, 256, 0, stream>>>(x, ln_g, ln_b, xn);
  wconv_kernel<<<N_DIM, 256, 0, stream>>>(W, wb);   // 3072 blocks * 256 * 4 = 3,145,728 elems
  gemm_gates  <<<dim3(M_DIM / BM, N_DIM / BN), 256, 0, stream>>>(xn, wb, bias, u_t, f_g, r_g);
  scan_pass1  <<<dim3(CH / 256, NSEG), 256, 0, stream>>>(f_g, u_t, Pseg, Eseg);
  scan_pass2  <<<CH / 256, 256, 0, stream>>>(Pseg, Eseg, c0, Cini, out + (size_t)M_DIM * DD);
  scan_pass3  <<<dim3(CH / 256, NSEG), 256, 0, stream>>>(f_g, u_t, r_g, x, xn, Cini, out);
}

// Round 2
// 337.897 us; speedup vs baseline: 1.0165x; 1.0165x over previous
//
#include <hip/hip_runtime.h>

#define L_DIM 2048
#define B_DIM 8
#define DD    1024
#define M_DIM 16384     // L*B
#define N_DIM 3072      // 3*D
#define K_DIM 1024
#define CH    8192      // B*D channels
#define CHV   2048      // CH/4
#define NSEG  64
#define LSEG  32
#define LN_EPS 1e-5f

typedef __attribute__((ext_vector_type(8))) short bf16x8;
typedef __attribute__((ext_vector_type(8))) unsigned short u16x8;
typedef __attribute__((ext_vector_type(4))) float f32x4;

__device__ __forceinline__ unsigned short f2bf(float f){
  unsigned u = __float_as_uint(f);
  u += 0x7fffu + ((u >> 16) & 1u);
  return (unsigned short)(u >> 16);
}
__device__ __forceinline__ float bf2f(unsigned short h){
  return __uint_as_float(((unsigned)h) << 16);
}
__device__ __forceinline__ float fsigmoid(float z){ return 1.0f/(1.0f + __expf(-z)); }
__device__ __forceinline__ float ftanh(float z){ return 1.0f - 2.0f/(1.0f + __expf(2.0f*z)); }

// ---------------- LayerNorm: x[M,1024] fp32 -> xn[M,1024] bf16 ----------------
__global__ __launch_bounds__(256) void ln_kernel(const float* __restrict__ x,
                                                 const float* __restrict__ g,
                                                 const float* __restrict__ bta,
                                                 unsigned short* __restrict__ xn)
{
  int row = blockIdx.x;
  int tid = threadIdx.x;
  const float4* xr = (const float4*)(x + (size_t)row * DD);
  float4 v = xr[tid];
  float s  = v.x + v.y + v.z + v.w;
  float sq = v.x*v.x + v.y*v.y + v.z*v.z + v.w*v.w;
  #pragma unroll
  for (int off = 32; off > 0; off >>= 1) {
    s  += __shfl_down(s,  off, 64);
    sq += __shfl_down(sq, off, 64);
  }
  __shared__ float ls[4], lsq[4];
  int wave = tid >> 6, lane = tid & 63;
  if (lane == 0) { ls[wave] = s; lsq[wave] = sq; }
  __syncthreads();
  s  = ls[0] + ls[1] + ls[2] + ls[3];
  sq = lsq[0] + lsq[1] + lsq[2] + lsq[3];
  float mean = s * (1.0f / DD);
  float var  = sq * (1.0f / DD) - mean * mean;
  float rstd = rsqrtf(var + LN_EPS);
  float4 gg = ((const float4*)g)[tid];
  float4 bb = ((const float4*)bta)[tid];
  ushort4 o;
  o.x = f2bf((v.x - mean) * rstd * gg.x + bb.x);
  o.y = f2bf((v.y - mean) * rstd * gg.y + bb.y);
  o.z = f2bf((v.z - mean) * rstd * gg.z + bb.z);
  o.w = f2bf((v.w - mean) * rstd * gg.w + bb.w);
  ((ushort4*)(xn + (size_t)row * DD))[tid] = o;
}

// ---------------- W fp32 [3072,1024] -> bf16 same layout ----------------
__global__ __launch_bounds__(256) void wconv_kernel(const float* __restrict__ W,
                                                    unsigned short* __restrict__ wb)
{
  int gid = blockIdx.x * 256 + threadIdx.x;
  float4 v = ((const float4*)W)[gid];
  ushort4 o;
  o.x = f2bf(v.x); o.y = f2bf(v.y); o.z = f2bf(v.z); o.w = f2bf(v.w);
  ((ushort4*)wb)[gid] = o;
}

// ---------------- GEMM: ufr = xn * W^T + b, fused activations ----------------
#define BM 128
#define BN 128
#define BK 32
#define LDP 136     // padded LDS row for epilogue transpose (272 B, 16B-aligned rows)

#define GLDS16(gp, lp) __builtin_amdgcn_global_load_lds( \
    (const __attribute__((address_space(1))) void*)(gp), \
    (__attribute__((address_space(3))) void*)(lp), 16, 0, 0)

__global__ __launch_bounds__(256) void gemm_gates(const unsigned short* __restrict__ A,
                                                  const unsigned short* __restrict__ Bw,
                                                  const float* __restrict__ bias,
                                                  unsigned short* __restrict__ u_t,
                                                  unsigned short* __restrict__ f_g,
                                                  unsigned short* __restrict__ r_g)
{
  __shared__ unsigned short smem[BM * LDP];       // 34,816 B; k-loop uses first 16 KB
  unsigned short* sA = smem;                      // BM*BK = 4096 ushorts
  unsigned short* sB = smem + BM * BK;            // BN*BK = 4096 ushorts
  int tid  = threadIdx.x;
  int wave = tid >> 6, lane = tid & 63;
  int bm0 = blockIdx.x * BM;
  int bn0 = blockIdx.y * BN;

  f32x4 zero = {0.f, 0.f, 0.f, 0.f};
  f32x4 acc[4][4];
  #pragma unroll
  for (int i = 0; i < 4; i++)
    #pragma unroll
    for (int j = 0; j < 4; j++) acc[i][j] = zero;

  int q  = lane >> 2;        // row within 16-row staging issue
  int rr = lane & 3;         // 8-element column chunk
  const unsigned short* a_base = A  + (size_t)(bm0 + wave * 32) * K_DIM + rr * 8;
  const unsigned short* b_base = Bw + (size_t)(bn0 + wave * 32) * K_DIM + rr * 8;

  int wm = (wave & 1) * 64, wn = (wave >> 1) * 64;
  int fm = lane & 15, quad = lane >> 4;

  for (int k0 = 0; k0 < K_DIM; k0 += BK) {
    #pragma unroll
    for (int i = 0; i < 2; i++) {
      GLDS16(a_base + (size_t)(i * 16 + q) * K_DIM + k0, &sA[(wave * 32 + i * 16) * BK]);
      GLDS16(b_base + (size_t)(i * 16 + q) * K_DIM + k0, &sB[(wave * 32 + i * 16) * BK]);
    }
    __syncthreads();

    bf16x8 af[4], bfr[4];
    #pragma unroll
    for (int i = 0; i < 4; i++) {
      af[i]  = *(const bf16x8*)&sA[(wm + i * 16 + fm) * BK + quad * 8];
      bfr[i] = *(const bf16x8*)&sB[(wn + i * 16 + fm) * BK + quad * 8];
    }
    #pragma unroll
    for (int mi = 0; mi < 4; mi++)
      #pragma unroll
      for (int ni = 0; ni < 4; ni++)
        acc[mi][ni] = __builtin_amdgcn_mfma_f32_16x16x32_bf16(af[mi], bfr[ni], acc[mi][ni], 0, 0, 0);
    __syncthreads();
  }

  // ---- epilogue: activate, transpose through LDS, coalesced store ----
  int slice = bn0 >> 10;            // 0:u 1:f 2:r (uniform per block; 128 | 1024)
  int nd0   = bn0 & 1023;
  unsigned short* dst = (slice == 0) ? u_t : ((slice == 1) ? f_g : r_g);

  #pragma unroll
  for (int ni = 0; ni < 4; ni++) {
    int lcol = wn + ni * 16 + fm;
    float bia = bias[bn0 + lcol];
    #pragma unroll
    for (int mi = 0; mi < 4; mi++) {
      #pragma unroll
      for (int reg = 0; reg < 4; reg++) {
        int lrow = wm + mi * 16 + quad * 4 + reg;
        float v = acc[mi][ni][reg] + bia;
        float act = (slice == 0) ? ftanh(v) : fsigmoid(v);
        smem[lrow * LDP + lcol] = f2bf(act);
      }
    }
  }
  __syncthreads();

  #pragma unroll
  for (int it = 0; it < 8; it++) {
    int row = it * 16 + (tid >> 4);
    int cc  = (tid & 15) * 8;
    u16x8 v = *(const u16x8*)&smem[row * LDP + cc];
    *(u16x8*)(dst + (size_t)(bm0 + row) * DD + nd0 + cc) = v;
  }
}

// ---------------- scan pass 1: per-segment affine summary (vec4) ----------------
__global__ __launch_bounds__(256) void scan_pass1(const unsigned short* __restrict__ f_g,
                                                  const unsigned short* __restrict__ u_t,
                                                  float* __restrict__ P, float* __restrict__ E)
{
  int v   = blockIdx.x * 256 + threadIdx.x;   // vec4-channel 0..2047
  int seg = blockIdx.y;
  const ushort4* f4 = (const ushort4*)f_g;
  const ushort4* u4 = (const ushort4*)u_t;
  size_t g = (size_t)seg * LSEG * CHV + v;
  float p0=1.f,p1=1.f,p2=1.f,p3=1.f, e0=0.f,e1=0.f,e2=0.f,e3=0.f;
  #pragma unroll 4
  for (int i = 0; i < LSEG; i++) {
    ushort4 ff = f4[g];
    ushort4 uu = u4[g];
    float fa=bf2f(ff.x), fb=bf2f(ff.y), fc=bf2f(ff.z), fd=bf2f(ff.w);
    e0 = fa*e0 + (1.f-fa)*bf2f(uu.x); p0 *= fa;
    e1 = fb*e1 + (1.f-fb)*bf2f(uu.y); p1 *= fb;
    e2 = fc*e2 + (1.f-fc)*bf2f(uu.z); p2 *= fc;
    e3 = fd*e3 + (1.f-fd)*bf2f(uu.w); p3 *= fd;
    g += CHV;
  }
  float4 pv = {p0,p1,p2,p3}, ev = {e0,e1,e2,e3};
  ((float4*)P)[(size_t)seg * CHV + v] = pv;
  ((float4*)E)[(size_t)seg * CHV + v] = ev;
}

// ---------------- scan pass 2: scan 64 segment summaries per channel ----------------
__global__ __launch_bounds__(64) void scan_pass2(const float* __restrict__ P,
                                                 const float* __restrict__ E,
                                                 const float* __restrict__ c0,
                                                 float* __restrict__ Cini,
                                                 float* __restrict__ lastc)
{
  int ch = blockIdx.x * 64 + threadIdx.x;     // 128 blocks x 64
  float c = c0[ch];
  #pragma unroll 8
  for (int s = 0; s < NSEG; s++) {
    Cini[(size_t)s * CH + ch] = c;
    c = P[(size_t)s * CH + ch] * c + E[(size_t)s * CH + ch];
  }
  lastc[ch] = c;
}

// ---------------- scan pass 3: replay with true init + fused output (vec4) -----
__global__ __launch_bounds__(256) void scan_pass3(const unsigned short* __restrict__ f_g,
                                                  const unsigned short* __restrict__ u_t,
                                                  const unsigned short* __restrict__ r_g,
                                                  const float* __restrict__ x,
                                                  const unsigned short* __restrict__ xn,
                                                  const float* __restrict__ Cini,
                                                  float* __restrict__ out)
{
  int v   = blockIdx.x * 256 + threadIdx.x;   // vec4-channel 0..2047
  int seg = blockIdx.y;
  const ushort4* f4 = (const ushort4*)f_g;
  const ushort4* u4 = (const ushort4*)u_t;
  const ushort4* r4 = (const ushort4*)r_g;
  const ushort4* n4 = (const ushort4*)xn;
  const float4*  x4 = (const float4*)x;
  float4*        o4 = (float4*)out;
  float4 c = ((const float4*)Cini)[(size_t)seg * CHV + v];
  size_t g = (size_t)seg * LSEG * CHV + v;
  #pragma unroll 4
  for (int i = 0; i < LSEG; i++) {
    ushort4 ff = f4[g];
    ushort4 uu = u4[g];
    ushort4 rr = r4[g];
    ushort4 nn = n4[g];
    float4 xv = x4[g];
    float fa=bf2f(ff.x), fb=bf2f(ff.y), fc=bf2f(ff.z), fd=bf2f(ff.w);
    c.x = fa*c.x + (1.f-fa)*bf2f(uu.x);
    c.y = fb*c.y + (1.f-fb)*bf2f(uu.y);
    c.z = fc*c.z + (1.f-fc)*bf2f(uu.z);
    c.w = fd*c.w + (1.f-fd)*bf2f(uu.w);
    float ra=bf2f(rr.x), rb=bf2f(rr.y), rc=bf2f(rr.z), rd=bf2f(rr.w);
    float4 ov;
    ov.x = xv.x + ra*ftanh(c.x) + (1.f-ra)*bf2f(nn.x);
    ov.y = xv.y + rb*ftanh(c.y) + (1.f-rb)*bf2f(nn.y);
    ov.z = xv.z + rc*ftanh(c.z) + (1.f-rc)*bf2f(nn.z);
    ov.w = xv.w + rd*ftanh(c.w) + (1.f-rd)*bf2f(nn.w);
    o4[g] = ov;
    g += CHV;
  }
}

extern "C" void kernel_launch(void* const* d_in, const int* in_sizes, int n_in,
                              void* d_out, int out_size, void* d_ws, size_t ws_size,
                              hipStream_t stream) {
  const float* x    = (const float*)d_in[0];
  const float* c0   = (const float*)d_in[1];
  const float* W    = (const float*)d_in[2];
  const float* bias = (const float*)d_in[3];
  const float* ln_g = (const float*)d_in[4];
  const float* ln_b = (const float*)d_in[5];
  float* out = (float*)d_out;

  char* ws = (char*)d_ws;
  unsigned short* xn  = (unsigned short*)(ws);                 // 33,554,432
  unsigned short* wb  = (unsigned short*)(ws + 33554432ULL);   //  6,291,456
  unsigned short* u_t = (unsigned short*)(ws + 39845888ULL);   // 33,554,432
  unsigned short* f_g = (unsigned short*)(ws + 73400320ULL);   // 33,554,432
  unsigned short* r_g = (unsigned short*)(ws + 106954752ULL);  // 33,554,432
  float* Pseg = (float*)(ws + 140509184ULL);                   //  2,097,152
  float* Eseg = (float*)(ws + 142606336ULL);                   //  2,097,152
  float* Cini = (float*)(ws + 144703488ULL);                   //  2,097,152

  ln_kernel   <<<M_DIM, 256, 0, stream>>>(x, ln_g, ln_b, xn);
  wconv_kernel<<<N_DIM, 256, 0, stream>>>(W, wb);
  gemm_gates  <<<dim3(M_DIM / BM, N_DIM / BN), 256, 0, stream>>>(xn, wb, bias, u_t, f_g, r_g);
  scan_pass1  <<<dim3(CHV / 256, NSEG), 256, 0, stream>>>(f_g, u_t, Pseg, Eseg);
  scan_pass2  <<<CH / 64, 64, 0, stream>>>(Pseg, Eseg, c0, Cini, out + (size_t)M_DIM * DD);
  scan_pass3  <<<dim3(CHV / 256, NSEG), 256, 0, stream>>>(f_g, u_t, r_g, x, xn, Cini, out);
}